// Round 1
// baseline (361.867 us; speedup 1.0000x reference)
//
#include <hip/hip_runtime.h>
#include <hip/hip_bf16.h>

// ---------------- problem constants ----------------
#define T_SEQ 8192
#define DMODEL 1024
#define DINNER 2048          // DI
#define NSTATE 16            // DS
#define NCH 128              // scan chunks
#define CL 64                // chunk length (NCH*CL = T_SEQ)

typedef __attribute__((ext_vector_type(8))) short bf16x8;   // 8 bf16 = 4 VGPRs (MFMA A/B frag)
typedef __attribute__((ext_vector_type(4))) float f32x4;    // MFMA C/D frag

__device__ __forceinline__ float bf2f(ushort u) {
  union { unsigned u; float f; } c; c.u = ((unsigned)u) << 16; return c.f;
}
__device__ __forceinline__ ushort f2bf(float f) {
  union { float f; unsigned u; } c; c.f = f;
  unsigned r = c.u + 0x7FFFu + ((c.u >> 16) & 1u);   // RNE
  return (ushort)(r >> 16);
}

// ---------------- prep kernels ----------------
__global__ __launch_bounds__(256) void cast_bf16(const float* __restrict__ in,
                                                 ushort* __restrict__ out, int n4) {
  int i = blockIdx.x * 256 + threadIdx.x;
  if (i < n4) {
    float4 v = ((const float4*)in)[i];
    ushort4 o;
    o.x = f2bf(v.x); o.y = f2bf(v.y); o.z = f2bf(v.z); o.w = f2bf(v.w);
    ((ushort4*)out)[i] = o;
  }
}

// in[R][C] f32 -> out[C][R] bf16   (grid: (C/32, R/32), block (32,8))
__global__ __launch_bounds__(256) void transpose_bf16(const float* __restrict__ in,
                                                      ushort* __restrict__ out, int R, int C) {
  __shared__ float tile[32][33];
  int bx = blockIdx.x * 32;   // C base
  int by = blockIdx.y * 32;   // R base
  int x = threadIdx.x, y = threadIdx.y;
#pragma unroll
  for (int j = 0; j < 32; j += 8)
    tile[y + j][x] = in[(size_t)(by + y + j) * C + bx + x];
  __syncthreads();
#pragma unroll
  for (int j = 0; j < 32; j += 8)
    out[(size_t)(bx + y + j) * R + by + x] = f2bf(tile[x][y + j]);
}

// W_x[2048][33] f32 -> wxT[128][2048] bf16 (transposed, zero-padded rows 33..127)
__global__ __launch_bounds__(256) void wx_transpose_pad(const float* __restrict__ Wx,
                                                        ushort* __restrict__ wxT) {
  int idx = blockIdx.x * 256 + threadIdx.x;   // 128*2048
  int j = idx >> 11;
  int k = idx & 2047;
  wxT[idx] = (j < 33) ? f2bf(Wx[k * 33 + j]) : (ushort)0;
}

// ---------------- GEMM: C[M][N] = A[M][K] * B^T, A/B bf16 row-major K-contig ----------------
// m97 structure: 128x128 tile, BK=32, 4 waves (2x2), 4x4 16x16x32 MFMA frags/wave,
// global_load_lds width-16 staging, 2 barriers per K-step.
template<int BF16OUT>
__global__ __launch_bounds__(256) void gemm_bt(const ushort* __restrict__ A,
                                               const ushort* __restrict__ B,
                                               void* __restrict__ Cout,
                                               int N, int K) {
  __shared__ __align__(16) ushort sA[128 * 32];
  __shared__ __align__(16) ushort sB[128 * 32];
  const int tid = threadIdx.x;
  const int lane = tid & 63;
  const int wid = tid >> 6;
  const int row0 = blockIdx.x * 128;
  const int col0 = blockIdx.y * 128;
  const int wm = wid >> 1, wn = wid & 1;

  // staging: thread tid covers bytes [16*tid,16*tid+16) of linear [128][32] bf16 tile
  const int lr = tid >> 2;            // tile row (0..63, +64 for second load)
  const int lk = (tid & 3) << 3;      // k element offset (0/8/16/24)
  const ushort* gA  = A + (size_t)(row0 + lr) * K + lk;
  const ushort* gA2 = gA + (size_t)64 * K;
  const ushort* gB  = B + (size_t)(col0 + lr) * K + lk;
  const ushort* gB2 = gB + (size_t)64 * K;
  ushort* dA = sA + wid * 512;        // wave-uniform LDS dest (HW adds lane*16B)
  ushort* dB = sB + wid * 512;

  f32x4 acc[4][4];
#pragma unroll
  for (int m = 0; m < 4; ++m)
#pragma unroll
    for (int n = 0; n < 4; ++n) acc[m][n] = (f32x4){0.f, 0.f, 0.f, 0.f};

  const int frow = lane & 15;         // fragment row/col within 16
  const int fk = (lane >> 4) << 3;    // fragment k offset (0/8/16/24)

  for (int k0 = 0; k0 < K; k0 += 32) {
    __builtin_amdgcn_global_load_lds((const __attribute__((address_space(1))) void*)(gA + k0),
                                     (__attribute__((address_space(3))) void*)dA, 16, 0, 0);
    __builtin_amdgcn_global_load_lds((const __attribute__((address_space(1))) void*)(gA2 + k0),
                                     (__attribute__((address_space(3))) void*)(dA + 2048), 16, 0, 0);
    __builtin_amdgcn_global_load_lds((const __attribute__((address_space(1))) void*)(gB + k0),
                                     (__attribute__((address_space(3))) void*)dB, 16, 0, 0);
    __builtin_amdgcn_global_load_lds((const __attribute__((address_space(1))) void*)(gB2 + k0),
                                     (__attribute__((address_space(3))) void*)(dB + 2048), 16, 0, 0);
    __syncthreads();

    bf16x8 av[4], bv[4];
#pragma unroll
    for (int m = 0; m < 4; ++m)
      av[m] = *(const bf16x8*)&sA[(wm * 64 + m * 16 + frow) * 32 + fk];
#pragma unroll
    for (int n = 0; n < 4; ++n)
      bv[n] = *(const bf16x8*)&sB[(wn * 64 + n * 16 + frow) * 32 + fk];
#pragma unroll
    for (int m = 0; m < 4; ++m)
#pragma unroll
      for (int n = 0; n < 4; ++n)
        acc[m][n] = __builtin_amdgcn_mfma_f32_16x16x32_bf16(av[m], bv[n], acc[m][n], 0, 0, 0);
    __syncthreads();
  }

  // epilogue: C/D layout col=lane&15, row=(lane>>4)*4+reg  [verified m89/m91]
  const int crow = row0 + wm * 64 + (lane >> 4) * 4;
  const int ccol = col0 + wn * 64 + (lane & 15);
#pragma unroll
  for (int m = 0; m < 4; ++m)
#pragma unroll
    for (int n = 0; n < 4; ++n)
#pragma unroll
      for (int j = 0; j < 4; ++j) {
        int r = crow + m * 16 + j;
        int c = ccol + n * 16;
        float v = acc[m][n][j];
        if (BF16OUT) ((ushort*)Cout)[(size_t)r * N + c] = f2bf(v);
        else         ((float*) Cout)[(size_t)r * N + c] = v;
      }
}

// ---------------- depthwise causal conv (DC=4) + silu ----------------
// xz: [T][4096] bf16 (first 2048 cols = xc). xs out: [T][2048] bf16.
__global__ __launch_bounds__(256) void conv_silu(const ushort* __restrict__ xz,
                                                 const float* __restrict__ cw,
                                                 const float* __restrict__ cb,
                                                 ushort* __restrict__ xs) {
  int idx = blockIdx.x * 256 + threadIdx.x;   // t*2048 + d
  int t = idx >> 11, d = idx & 2047;
  float4 w = *(const float4*)(cw + d * 4);
  float a = cb[d];
  const float wk[4] = {w.x, w.y, w.z, w.w};
#pragma unroll
  for (int k = 0; k < 4; ++k) {
    int tt = t - 3 + k;
    if (tt >= 0) a += bf2f(xz[(size_t)tt * 4096 + d]) * wk[k];
  }
  float s = a / (1.f + expf(-a));
  xs[idx] = f2bf(s);
}

// ---------------- scan precompute ----------------
// xdbl: [T][128] f32 (cols 0..32 valid). Outputs abar/bbar/cc [T][16], delta [T].
__global__ __launch_bounds__(256) void precompute_k(const float* __restrict__ xdbl,
                                                    const float* __restrict__ A_log,
                                                    float* __restrict__ abar,
                                                    float* __restrict__ bbar,
                                                    float* __restrict__ cc,
                                                    float* __restrict__ dlt) {
  int t = blockIdx.x * 256 + threadIdx.x;
  if (t >= T_SEQ) return;
  const float* r = xdbl + (size_t)t * 128;
  float v = r[0];
  float delta = (v > 20.f) ? v : log1pf(expf(v));
  dlt[t] = delta;
#pragma unroll
  for (int n = 0; n < NSTATE; ++n) {
    float A = -expf(A_log[n]);
    abar[t * 16 + n] = expf(delta * A);
    bbar[t * 16 + n] = delta * r[1 + n];
    cc[t * 16 + n]   = r[17 + n];
  }
}

// P[c][n] = prod_{t in chunk} abar[t][n] = exp(A_n * sum delta)
__global__ __launch_bounds__(256) void chunkprod_k(const float* __restrict__ dlt,
                                                   const float* __restrict__ A_log,
                                                   float* __restrict__ P) {
  int idx = blockIdx.x * 256 + threadIdx.x;
  if (idx >= NCH * NSTATE) return;
  int c = idx >> 4, n = idx & 15;
  float s = 0.f;
  for (int i = 0; i < CL; ++i) s += dlt[c * CL + i];
  P[idx] = expf(-expf(A_log[n]) * s);
}

// ---------------- scan pass 1: per-chunk local end-state (h0=0) ----------------
__global__ __launch_bounds__(256) void scan1(const ushort* __restrict__ xs,
                                             const float* __restrict__ abar,
                                             const float* __restrict__ bbar,
                                             float* __restrict__ hend) {
  int c = blockIdx.x;                  // chunk
  int d = blockIdx.y * 256 + threadIdx.x;
  __shared__ float s_ab[CL * 16], s_bb[CL * 16];
  for (int e = threadIdx.x; e < CL * 16; e += 256) {
    s_ab[e] = abar[(size_t)c * CL * 16 + e];
    s_bb[e] = bbar[(size_t)c * CL * 16 + e];
  }
  __syncthreads();
  float h[16];
#pragma unroll
  for (int n = 0; n < 16; ++n) h[n] = 0.f;
  int tbase = c * CL;
  for (int i = 0; i < CL; ++i) {
    float x = bf2f(xs[(size_t)(tbase + i) * DINNER + d]);
#pragma unroll
    for (int n = 0; n < 16; ++n) h[n] = s_ab[i * 16 + n] * h[n] + s_bb[i * 16 + n] * x;
  }
  float* o = hend + ((size_t)c * DINNER + d) * 16;
#pragma unroll
  for (int q = 0; q < 4; ++q)
    ((float4*)o)[q] = make_float4(h[4 * q], h[4 * q + 1], h[4 * q + 2], h[4 * q + 3]);
}

// ---------------- scan pass 2: carry scan across chunks ----------------
__global__ __launch_bounds__(256) void scan2(const float* __restrict__ hend,
                                             const float* __restrict__ P,
                                             float* __restrict__ hin) {
  int idx = blockIdx.x * 256 + threadIdx.x;   // d*16 + n, over 32768
  int n = idx & 15;
  float h = 0.f;
  for (int c = 0; c < NCH; ++c) {
    hin[(size_t)c * (DINNER * 16) + idx] = h;
    h = P[c * 16 + n] * h + hend[(size_t)c * (DINNER * 16) + idx];
  }
}

// ---------------- scan pass 3: replay with carry-in, fuse D*xs + silu(z) gate ----------------
__global__ __launch_bounds__(256) void scan3(const ushort* __restrict__ xs,
                                             const ushort* __restrict__ xz,
                                             const float* __restrict__ abar,
                                             const float* __restrict__ bbar,
                                             const float* __restrict__ cc,
                                             const float* __restrict__ hin,
                                             const float* __restrict__ Dv,
                                             ushort* __restrict__ y) {
  int c = blockIdx.x;
  int d = blockIdx.y * 256 + threadIdx.x;
  __shared__ float s_ab[CL * 16], s_bb[CL * 16], s_cc[CL * 16];
  for (int e = threadIdx.x; e < CL * 16; e += 256) {
    s_ab[e] = abar[(size_t)c * CL * 16 + e];
    s_bb[e] = bbar[(size_t)c * CL * 16 + e];
    s_cc[e] = cc[(size_t)c * CL * 16 + e];
  }
  __syncthreads();
  float h[16];
  const float* hi = hin + ((size_t)c * DINNER + d) * 16;
#pragma unroll
  for (int q = 0; q < 4; ++q) {
    float4 v = ((const float4*)hi)[q];
    h[4 * q] = v.x; h[4 * q + 1] = v.y; h[4 * q + 2] = v.z; h[4 * q + 3] = v.w;
  }
  float Dd = Dv[d];
  int tbase = c * CL;
  for (int i = 0; i < CL; ++i) {
    size_t t = tbase + i;
    float x = bf2f(xs[t * DINNER + d]);
    float ys = 0.f;
#pragma unroll
    for (int n = 0; n < 16; ++n) {
      h[n] = s_ab[i * 16 + n] * h[n] + s_bb[i * 16 + n] * x;
      ys += s_cc[i * 16 + n] * h[n];
    }
    float z = bf2f(xz[t * 4096 + 2048 + d]);
    float yv = (ys + Dd * x) * (z / (1.f + expf(-z)));
    y[t * DINNER + d] = f2bf(yv);
  }
}

// ---------------- launch ----------------
extern "C" void kernel_launch(void* const* d_in, const int* in_sizes, int n_in,
                              void* d_out, int out_size, void* d_ws, size_t ws_size,
                              hipStream_t stream) {
  const float* x      = (const float*)d_in[0];   // [8192][1024]
  const float* W_in   = (const float*)d_in[1];   // [1024][4096]
  const float* conv_w = (const float*)d_in[2];   // [2048][1][4]
  const float* conv_b = (const float*)d_in[3];   // [2048]
  const float* W_x    = (const float*)d_in[4];   // [2048][33]
  const float* A_log  = (const float*)d_in[5];   // [16]
  const float* Dv     = (const float*)d_in[6];   // [2048]
  // d_in[7] = W_out [2048][1024]
  const float* W_out  = (const float*)d_in[7];
  float* out = (float*)d_out;                    // [8192][1024]

  char* w = (char*)d_ws;
  auto alloc = [&](size_t bytes) { char* p = w; w += (bytes + 255) & ~(size_t)255; return p; };

  ushort* xbf   = (ushort*)alloc((size_t)T_SEQ * DMODEL * 2);          // 16.8 MB
  ushort* winT  = (ushort*)alloc((size_t)4096 * 1024 * 2);             //  8.4 MB
  ushort* woutT = (ushort*)alloc((size_t)1024 * 2048 * 2);             //  4.2 MB
  ushort* wxT   = (ushort*)alloc((size_t)128 * 2048 * 2);              //  0.5 MB
  ushort* xz    = (ushort*)alloc((size_t)T_SEQ * 4096 * 2);            // 67.1 MB
  ushort* xs    = (ushort*)alloc((size_t)T_SEQ * DINNER * 2);          // 33.6 MB
  float*  xdbl  = (float*) alloc((size_t)T_SEQ * 128 * 4);             //  4.2 MB
  float*  abar  = (float*) alloc((size_t)T_SEQ * 16 * 4);
  float*  bbar  = (float*) alloc((size_t)T_SEQ * 16 * 4);
  float*  ccb   = (float*) alloc((size_t)T_SEQ * 16 * 4);
  float*  dlt   = (float*) alloc((size_t)T_SEQ * 4);
  float*  P     = (float*) alloc((size_t)NCH * 16 * 4);
  float*  hend  = (float*) alloc((size_t)NCH * DINNER * 16 * 4);       // 16.8 MB
  float*  hin   = (float*) alloc((size_t)NCH * DINNER * 16 * 4);       // 16.8 MB
  ushort* ybf   = (ushort*)alloc((size_t)T_SEQ * DINNER * 2);          // 33.6 MB

  // prep
  cast_bf16<<<(T_SEQ * DMODEL / 4 + 255) / 256, 256, 0, stream>>>(x, xbf, T_SEQ * DMODEL / 4);
  transpose_bf16<<<dim3(4096 / 32, 1024 / 32), dim3(32, 8), 0, stream>>>(W_in, winT, 1024, 4096);
  transpose_bf16<<<dim3(1024 / 32, 2048 / 32), dim3(32, 8), 0, stream>>>(W_out, woutT, 2048, 1024);
  wx_transpose_pad<<<(128 * 2048) / 256, 256, 0, stream>>>(W_x, wxT);

  // GEMM1: xz = x @ W_in   (8192 x 4096, K=1024), bf16 out
  gemm_bt<1><<<dim3(T_SEQ / 128, 4096 / 128), 256, 0, stream>>>(xbf, winT, xz, 4096, 1024);

  // conv + silu
  conv_silu<<<(T_SEQ * DINNER) / 256, 256, 0, stream>>>(xz, conv_w, conv_b, xs);

  // GEMM2: xdbl = xs @ W_x (padded to N=128), f32 out
  gemm_bt<0><<<dim3(T_SEQ / 128, 1), 256, 0, stream>>>(xs, wxT, xdbl, 128, 2048);

  // scan precompute
  precompute_k<<<T_SEQ / 256, 256, 0, stream>>>(xdbl, A_log, abar, bbar, ccb, dlt);
  chunkprod_k<<<(NCH * 16 + 255) / 256, 256, 0, stream>>>(dlt, A_log, P);

  // 3-pass chunked scan
  scan1<<<dim3(NCH, DINNER / 256), 256, 0, stream>>>(xs, abar, bbar, hend);
  scan2<<<(DINNER * 16) / 256, 256, 0, stream>>>(hend, P, hin);
  scan3<<<dim3(NCH, DINNER / 256), 256, 0, stream>>>(xs, xz, abar, bbar, ccb, hin, Dv, ybf);

  // GEMM3: out = y @ W_out (8192 x 1024, K=2048), f32 out
  gemm_bt<0><<<dim3(T_SEQ / 128, 1024 / 128), 256, 0, stream>>>(ybf, woutT, out, 1024, 2048);
}